// Round 1
// baseline (467.571 us; speedup 1.0000x reference)
//
#include <hip/hip_runtime.h>

// Problem constants (fixed by reference: seq (16,4096,1024) fp32, prune 0.5)
#define BATCH 16
#define NTOK  4096
#define DIM   1024
#define KSEL  2048              // kept tokens
#define NPRUNE 2048             // pruned tokens
#define SUM_CHUNKS 32           // partial-sum blocks per batch
#define ROWS_PER_CHUNK 64       // 2048 / 32

// ---------------------------------------------------------------------------
// Kernel 1: per-batch bitonic full sort of (weight, index) pairs.
// Order: value descending, index ascending on ties (matches jax.lax.top_k).
// Writes selected indices (positions 0..2047) and pruned indices (2048..4095).
// ---------------------------------------------------------------------------
__global__ __launch_bounds__(1024) void topk_sort_kernel(
    const float* __restrict__ w, int* __restrict__ sel, int* __restrict__ pr) {
  __shared__ float v[NTOK];
  __shared__ int   ix[NTOK];
  const int b = blockIdx.x;
  const float* wb = w + (size_t)b * NTOK;
  for (int i = threadIdx.x; i < NTOK; i += 1024) { v[i] = wb[i]; ix[i] = i; }
  __syncthreads();

  for (int k = 2; k <= NTOK; k <<= 1) {
    for (int j = k >> 1; j > 0; j >>= 1) {
      for (int i = threadIdx.x; i < NTOK; i += 1024) {
        const int p = i ^ j;
        if (p > i) {
          const float vi = v[i], vp = v[p];
          const int   ii = ix[i], ip = ix[p];
          // "before" == should appear earlier in final order
          const bool before = (vi > vp) || (vi == vp && ii < ip);
          const bool up = ((i & k) == 0);
          if (up ? !before : before) {
            v[i] = vp; v[p] = vi; ix[i] = ip; ix[p] = ii;
          }
        }
      }
      __syncthreads();
    }
  }

  for (int i = threadIdx.x; i < KSEL; i += 1024)   sel[b * KSEL + i]   = ix[i];
  for (int i = threadIdx.x; i < NPRUNE; i += 1024) pr[b * NPRUNE + i]  = ix[KSEL + i];
}

// ---------------------------------------------------------------------------
// Kernel 2: fused gather (selected rows -> out) + partial sums of pruned rows.
// grid = (KSEL + SUM_CHUNKS, BATCH), block = 256.
//   x-block < KSEL : copy one selected row (256 threads x float4 = 1024 floats)
//   else           : accumulate 64 pruned rows into a float4 partial
// ---------------------------------------------------------------------------
__global__ __launch_bounds__(256) void gather_partial_kernel(
    const float* __restrict__ seq, const int* __restrict__ sel,
    const int* __restrict__ pr, float* __restrict__ out,
    float* __restrict__ part) {
  const int b = blockIdx.y;
  const int t = blockIdx.x;
  const float4* seqb = (const float4*)(seq + (size_t)b * NTOK * DIM);

  if (t < KSEL) {
    const int row = sel[b * KSEL + t];
    const float4* src = seqb + (size_t)row * (DIM / 4);
    float4* dst = (float4*)(out + (size_t)b * (KSEL + 1) * DIM + (size_t)t * DIM);
    dst[threadIdx.x] = src[threadIdx.x];
  } else {
    const int c = t - KSEL;                       // 0..SUM_CHUNKS-1
    const int* prb = pr + b * NPRUNE + c * ROWS_PER_CHUNK;
    float4 acc = make_float4(0.f, 0.f, 0.f, 0.f);
    for (int r = 0; r < ROWS_PER_CHUNK; ++r) {
      const int row = prb[r];                     // wave-uniform, broadcast
      const float4 x = seqb[(size_t)row * (DIM / 4) + threadIdx.x];
      acc.x += x.x; acc.y += x.y; acc.z += x.z; acc.w += x.w;
    }
    float4* pdst = (float4*)(part + ((size_t)b * SUM_CHUNKS + c) * DIM);
    pdst[threadIdx.x] = acc;
  }
}

// ---------------------------------------------------------------------------
// Kernel 3: reduce SUM_CHUNKS partials per batch, scale, write out row 2048.
// ---------------------------------------------------------------------------
__global__ __launch_bounds__(256) void reduce_kernel(
    const float* __restrict__ part, float* __restrict__ out, float scale) {
  const int b = blockIdx.x;
  const float4* p = (const float4*)(part + (size_t)b * SUM_CHUNKS * DIM);
  float4 acc = make_float4(0.f, 0.f, 0.f, 0.f);
  for (int c = 0; c < SUM_CHUNKS; ++c) {
    const float4 x = p[(size_t)c * (DIM / 4) + threadIdx.x];
    acc.x += x.x; acc.y += x.y; acc.z += x.z; acc.w += x.w;
  }
  float4* dst = (float4*)(out + (size_t)b * (KSEL + 1) * DIM + (size_t)KSEL * DIM);
  float4 r;
  r.x = acc.x * scale; r.y = acc.y * scale;
  r.z = acc.z * scale; r.w = acc.w * scale;
  dst[threadIdx.x] = r;
}

extern "C" void kernel_launch(void* const* d_in, const int* in_sizes, int n_in,
                              void* d_out, int out_size, void* d_ws, size_t ws_size,
                              hipStream_t stream) {
  (void)in_sizes; (void)n_in; (void)out_size; (void)ws_size;
  const float* seq = (const float*)d_in[0];
  const float* w   = (const float*)d_in[1];
  float* out = (float*)d_out;

  // workspace layout: sel idx | pruned idx | partial sums
  int* sel = (int*)d_ws;                         // BATCH*KSEL ints
  int* pr  = sel + BATCH * KSEL;                 // BATCH*NPRUNE ints
  float* part = (float*)(pr + BATCH * NPRUNE);   // BATCH*SUM_CHUNKS*DIM floats

  topk_sort_kernel<<<BATCH, 1024, 0, stream>>>(w, sel, pr);
  gather_partial_kernel<<<dim3(KSEL + SUM_CHUNKS, BATCH), 256, 0, stream>>>(
      seq, sel, pr, out, part);
  const float scale = (float)(0.05 / (2048.0 + 1e-10));
  reduce_kernel<<<BATCH, 256, 0, stream>>>(part, out, scale);
}

// Round 2
// 453.357 us; speedup vs baseline: 1.0314x; 1.0314x over previous
//
#include <hip/hip_runtime.h>

// Problem constants (fixed by reference: seq (16,4096,1024) fp32, prune 0.5)
#define BATCH 16
#define NTOK  4096
#define DIM   1024
#define KSEL  2048                       // kept tokens
#define NPRUNE 2048                      // pruned tokens
#define SLICES (NTOK / 256)              // rank kernel x-blocks per batch = 16
#define SUM_CHUNKS 64                    // pruned-sum partial blocks per batch
#define ROWS_PER_CHUNK (NPRUNE / SUM_CHUNKS)  // 32
#define COPY_ROWS 4                      // selected rows copied per block
#define NCOPY (KSEL / COPY_ROWS)         // 512

// ---------------------------------------------------------------------------
// Kernel 1: all-pairs rank computation (replaces bitonic sort).
// key(i) = (~sortable(w_i) << 32) | i  — ascending u64 order == jax.lax.top_k
// order (value desc, index asc). rank(i) = #{j : key(j) < key(i)}; keys are
// unique (index in low bits). Scatter: rank<KSEL -> sel[rank]=i else pruned.
// grid (SLICES, BATCH) x 256: one block per CU, barrier-free inner loop of
// broadcast ds_read_b128 + 2x v_cmp_lt_u64.
// ---------------------------------------------------------------------------
__global__ __launch_bounds__(256) void rank_kernel(
    const float* __restrict__ w, int* __restrict__ sel, int* __restrict__ pr) {
  __shared__ unsigned long long keys[NTOK];   // 32 KB
  const int b = blockIdx.y;
  const float* wb = w + (size_t)b * NTOK;
  for (int j = threadIdx.x; j < NTOK; j += 256) {
    const unsigned int u = __float_as_uint(wb[j]);
    // monotone float->u32 map (ascending), then invert for descending
    const unsigned int s = (u & 0x80000000u) ? ~u : (u | 0x80000000u);
    keys[j] = ((unsigned long long)(~s) << 32) | (unsigned int)j;
  }
  __syncthreads();

  const int i = blockIdx.x * 256 + threadIdx.x;
  const unsigned long long ki = keys[i];
  const ulonglong2* k2 = (const ulonglong2*)keys;
  unsigned int rank = 0;
#pragma unroll 8
  for (int j = 0; j < NTOK / 2; ++j) {
    const ulonglong2 kk = k2[j];           // broadcast read: conflict-free
    rank += (kk.x < ki);
    rank += (kk.y < ki);
  }
  if (rank < KSEL) sel[b * KSEL + rank] = i;
  else             pr[b * NPRUNE + (rank - KSEL)] = i;
}

// ---------------------------------------------------------------------------
// Kernel 2: fused gather + pruned partial sums. Sum chunks FIRST in grid.x
// (they're the heavy blocks — no tail), then copy blocks (4 rows each for
// memory-level parallelism).
// grid = (SUM_CHUNKS + NCOPY, BATCH), block = 256.
// ---------------------------------------------------------------------------
__global__ __launch_bounds__(256) void gather_partial_kernel(
    const float* __restrict__ seq, const int* __restrict__ sel,
    const int* __restrict__ pr, float* __restrict__ out,
    float* __restrict__ part) {
  const int b = blockIdx.y;
  const int t = blockIdx.x;
  const float4* seqb = (const float4*)(seq + (size_t)b * NTOK * DIM);
  const int lane = threadIdx.x;

  if (t < SUM_CHUNKS) {
    const int* prb = pr + b * NPRUNE + t * ROWS_PER_CHUNK;
    float4 a0 = make_float4(0.f, 0.f, 0.f, 0.f), a1 = a0, a2 = a0, a3 = a0;
    for (int r = 0; r < ROWS_PER_CHUNK; r += 4) {
      const int r0 = prb[r + 0], r1 = prb[r + 1];
      const int r2 = prb[r + 2], r3 = prb[r + 3];
      const float4 x0 = seqb[(size_t)r0 * (DIM / 4) + lane];
      const float4 x1 = seqb[(size_t)r1 * (DIM / 4) + lane];
      const float4 x2 = seqb[(size_t)r2 * (DIM / 4) + lane];
      const float4 x3 = seqb[(size_t)r3 * (DIM / 4) + lane];
      a0.x += x0.x; a0.y += x0.y; a0.z += x0.z; a0.w += x0.w;
      a1.x += x1.x; a1.y += x1.y; a1.z += x1.z; a1.w += x1.w;
      a2.x += x2.x; a2.y += x2.y; a2.z += x2.z; a2.w += x2.w;
      a3.x += x3.x; a3.y += x3.y; a3.z += x3.z; a3.w += x3.w;
    }
    float4 acc;
    acc.x = (a0.x + a1.x) + (a2.x + a3.x);
    acc.y = (a0.y + a1.y) + (a2.y + a3.y);
    acc.z = (a0.z + a1.z) + (a2.z + a3.z);
    acc.w = (a0.w + a1.w) + (a2.w + a3.w);
    float4* pdst = (float4*)(part + ((size_t)b * SUM_CHUNKS + t) * DIM);
    pdst[lane] = acc;
  } else {
    const int c = t - SUM_CHUNKS;            // 0..NCOPY-1
    const int base = c * COPY_ROWS;
    const int* selb = sel + b * KSEL + base;
    const int i0 = selb[0], i1 = selb[1], i2 = selb[2], i3 = selb[3];
    const float4 x0 = seqb[(size_t)i0 * (DIM / 4) + lane];
    const float4 x1 = seqb[(size_t)i1 * (DIM / 4) + lane];
    const float4 x2 = seqb[(size_t)i2 * (DIM / 4) + lane];
    const float4 x3 = seqb[(size_t)i3 * (DIM / 4) + lane];
    float4* dst = (float4*)(out + (size_t)b * (KSEL + 1) * DIM +
                            (size_t)base * DIM);
    dst[0 * (DIM / 4) + lane] = x0;
    dst[1 * (DIM / 4) + lane] = x1;
    dst[2 * (DIM / 4) + lane] = x2;
    dst[3 * (DIM / 4) + lane] = x3;
  }
}

// ---------------------------------------------------------------------------
// Kernel 3: reduce SUM_CHUNKS partials per batch, scale, write out row KSEL.
// ---------------------------------------------------------------------------
__global__ __launch_bounds__(256) void reduce_kernel(
    const float* __restrict__ part, float* __restrict__ out, float scale) {
  const int b = blockIdx.x;
  const float4* p = (const float4*)(part + (size_t)b * SUM_CHUNKS * DIM);
  float4 acc = make_float4(0.f, 0.f, 0.f, 0.f);
  for (int c = 0; c < SUM_CHUNKS; ++c) {
    const float4 x = p[(size_t)c * (DIM / 4) + threadIdx.x];
    acc.x += x.x; acc.y += x.y; acc.z += x.z; acc.w += x.w;
  }
  float4* dst = (float4*)(out + (size_t)b * (KSEL + 1) * DIM +
                          (size_t)KSEL * DIM);
  float4 r;
  r.x = acc.x * scale; r.y = acc.y * scale;
  r.z = acc.z * scale; r.w = acc.w * scale;
  dst[threadIdx.x] = r;
}

extern "C" void kernel_launch(void* const* d_in, const int* in_sizes, int n_in,
                              void* d_out, int out_size, void* d_ws, size_t ws_size,
                              hipStream_t stream) {
  (void)in_sizes; (void)n_in; (void)out_size; (void)ws_size;
  const float* seq = (const float*)d_in[0];
  const float* w   = (const float*)d_in[1];
  float* out = (float*)d_out;

  // workspace layout: sel idx | pruned idx | partial sums
  int* sel = (int*)d_ws;                         // BATCH*KSEL ints
  int* pr  = sel + BATCH * KSEL;                 // BATCH*NPRUNE ints
  float* part = (float*)(pr + BATCH * NPRUNE);   // BATCH*SUM_CHUNKS*DIM floats

  rank_kernel<<<dim3(SLICES, BATCH), 256, 0, stream>>>(w, sel, pr);
  gather_partial_kernel<<<dim3(SUM_CHUNKS + NCOPY, BATCH), 256, 0, stream>>>(
      seq, sel, pr, out, part);
  const float scale = (float)(0.05 / (2048.0 + 1e-10));
  reduce_kernel<<<BATCH, 256, 0, stream>>>(part, out, scale);
}